// Round 1
// baseline (63.309 us; speedup 1.0000x reference)
//
#include <hip/hip_runtime.h>

#define IMG_H 384
#define IMG_W 512
#define TILE_W 64
#define TILE_H 16
#define HALO_W (TILE_W + 2)
#define HALO_H (TILE_H + 2)

__device__ __forceinline__ int reflect_idx(int i, int n) {
    // ReflectionPad2d(1): -1 -> 1, n -> n-2
    if (i < 0) i = -i;
    else if (i >= n) i = 2 * n - 2 - i;
    return i;
}

__global__ __launch_bounds__(512) void ssim_kernel(
    const float* __restrict__ pred,
    const float* __restrict__ target,
    float* __restrict__ out)
{
    __shared__ float lp[HALO_H][HALO_W];
    __shared__ float lt[HALO_H][HALO_W];

    const int plane  = blockIdx.z;                 // B*C planes
    const int tile_x = blockIdx.x * TILE_W;
    const int tile_y = blockIdx.y * TILE_H;
    const size_t base = (size_t)plane * (IMG_H * IMG_W);

    const int tid = threadIdx.y * TILE_W + threadIdx.x;   // 0..511

    // Cooperative halo load with reflection
    for (int i = tid; i < HALO_H * HALO_W; i += 512) {
        int ly = i / HALO_W;
        int lx = i - ly * HALO_W;
        int gy = reflect_idx(tile_y - 1 + ly, IMG_H);
        int gx = reflect_idx(tile_x - 1 + lx, IMG_W);
        size_t idx = base + (size_t)gy * IMG_W + gx;
        lp[ly][lx] = pred[idx];
        lt[ly][lx] = target[idx];
    }
    __syncthreads();

    const float C1 = 1e-4f;   // 0.01^2
    const float C2 = 9e-4f;   // 0.03^2
    const float inv9 = 1.0f / 9.0f;

    #pragma unroll
    for (int k = 0; k < 2; ++k) {
        const int ly = threadIdx.y + k * 8;   // output row within tile
        const int lx = threadIdx.x;           // output col within tile

        float s_p = 0.f, s_t = 0.f, s_pp = 0.f, s_tt = 0.f, s_pt = 0.f;
        #pragma unroll
        for (int dy = 0; dy < 3; ++dy) {
            #pragma unroll
            for (int dx = 0; dx < 3; ++dx) {
                float p = lp[ly + dy][lx + dx];
                float t = lt[ly + dy][lx + dx];
                s_p += p;
                s_t += t;
                s_pp = fmaf(p, p, s_pp);
                s_tt = fmaf(t, t, s_tt);
                s_pt = fmaf(p, t, s_pt);
            }
        }

        float up = s_p * inv9;
        float ut = s_t * inv9;
        float sig_p  = s_pp * inv9 - up * up;
        float sig_t  = s_tt * inv9 - ut * ut;
        float sig_co = s_pt * inv9 - up * ut;

        float num = (2.f * up * ut + C1) * (2.f * sig_co + C2);
        float den = (up * up + ut * ut + C1) * (sig_p + sig_t + C2);
        float v = (1.f - num / den) * 0.5f;
        v = fminf(fmaxf(v, 0.f), 1.f);

        out[base + (size_t)(tile_y + ly) * IMG_W + (tile_x + lx)] = v;
    }
}

extern "C" void kernel_launch(void* const* d_in, const int* in_sizes, int n_in,
                              void* d_out, int out_size, void* d_ws, size_t ws_size,
                              hipStream_t stream) {
    const float* pred   = (const float*)d_in[0];
    const float* target = (const float*)d_in[1];
    float* out = (float*)d_out;

    const int planes = in_sizes[0] / (IMG_H * IMG_W);   // 32*3 = 96

    dim3 block(TILE_W, 8);
    dim3 grid(IMG_W / TILE_W, IMG_H / TILE_H, planes);
    ssim_kernel<<<grid, block, 0, stream>>>(pred, target, out);
}

// Round 2
// 61.976 us; speedup vs baseline: 1.0215x; 1.0215x over previous
//
#include <hip/hip_runtime.h>

#define IMG_H 384
#define IMG_W 512
#define TILE_W 64
#define TILE_H 32
#define HALO_H (TILE_H + 2)        // 34
#define LDS_STRIDE 72              // floats; halo col c lives at index c+3 (keeps b128 16B-aligned)
#define NTHREADS 512

__device__ __forceinline__ int reflect_idx(int i, int n) {
    // ReflectionPad2d(1): -1 -> 1, n -> n-2
    if (i < 0) i = -i;
    else if (i >= n) i = 2 * n - 2 - i;
    return i;
}

__global__ __launch_bounds__(NTHREADS) void ssim_kernel(
    const float* __restrict__ pred,
    const float* __restrict__ target,
    float* __restrict__ out)
{
    __shared__ float lp[HALO_H * LDS_STRIDE];
    __shared__ float lt[HALO_H * LDS_STRIDE];

    const int plane  = blockIdx.z;
    const int tile_x = blockIdx.x * TILE_W;
    const int tile_y = blockIdx.y * TILE_H;
    const size_t base = (size_t)plane * (IMG_H * IMG_W);

    const int tid = threadIdx.y * 16 + threadIdx.x;    // 0..511

    // ---- halo load: rows 0..33, interior (halo cols 1..64) as aligned float4 ----
    // 34 rows * 16 float4 = 544 items per array; row = i>>4 (no divide)
    {
        const float* __restrict__ src = pred;
        float* dst = lp;
        #pragma unroll
        for (int a = 0; a < 2; ++a) {
            for (int i = tid; i < HALO_H * 16; i += NTHREADS) {
                int row = i >> 4;
                int c4  = i & 15;
                int gy  = reflect_idx(tile_y - 1 + row, IMG_H);
                float4 v = *(const float4*)(src + base + (size_t)gy * IMG_W + tile_x + c4 * 4);
                *(float4*)(dst + row * LDS_STRIDE + 4 + c4 * 4) = v;
            }
            src = target;
            dst = lt;
        }
    }
    // ---- halo edge columns (halo col 0 and 65): 34 rows * 2 cols * 2 arrays = 136 loads ----
    if (tid < HALO_H * 4) {
        int row = tid >> 2;
        int sub = tid & 3;
        const float* __restrict__ src = (sub & 2) ? target : pred;
        float* dst = (sub & 2) ? lt : lp;
        int hc = (sub & 1) ? 65 : 0;
        int gy = reflect_idx(tile_y - 1 + row, IMG_H);
        int gx = reflect_idx(tile_x - 1 + hc, IMG_W);
        dst[row * LDS_STRIDE + 3 + hc] = src[base + (size_t)gy * IMG_W + gx];
    }
    __syncthreads();

    // ---- compute: each thread -> 1 row, 4 consecutive output columns ----
    const int oy = threadIdx.y;            // output row in tile (needs halo rows oy..oy+2)
    const int lx = threadIdx.x;            // column group: outputs 4lx..4lx+3, halo cols 4lx..4lx+5

    float cs_p[6], cs_t[6], cs_pp[6], cs_tt[6], cs_pt[6];
    #pragma unroll
    for (int c = 0; c < 6; ++c) {
        cs_p[c] = 0.f; cs_t[c] = 0.f; cs_pp[c] = 0.f; cs_tt[c] = 0.f; cs_pt[c] = 0.f;
    }

    #pragma unroll
    for (int dy = 0; dy < 3; ++dy) {
        const float* rp = lp + (oy + dy) * LDS_STRIDE + 4 * lx;
        const float* rt = lt + (oy + dy) * LDS_STRIDE + 4 * lx;
        float  pe0 = rp[3];
        float4 pm  = *(const float4*)(rp + 4);
        float  pe5 = rp[8];
        float  te0 = rt[3];
        float4 tm  = *(const float4*)(rt + 4);
        float  te5 = rt[8];
        float pv[6] = {pe0, pm.x, pm.y, pm.z, pm.w, pe5};
        float tv[6] = {te0, tm.x, tm.y, tm.z, tm.w, te5};
        #pragma unroll
        for (int c = 0; c < 6; ++c) {
            float p = pv[c], t = tv[c];
            cs_p[c]  += p;
            cs_t[c]  += t;
            cs_pp[c] = fmaf(p, p, cs_pp[c]);
            cs_tt[c] = fmaf(t, t, cs_tt[c]);
            cs_pt[c] = fmaf(p, t, cs_pt[c]);
        }
    }

    const float C1 = 1e-4f;    // 0.01^2
    const float C2 = 9e-4f;    // 0.03^2
    const float inv9 = 1.0f / 9.0f;

    float resv[4];
    #pragma unroll
    for (int j = 0; j < 4; ++j) {
        float s_p  = cs_p[j]  + cs_p[j+1]  + cs_p[j+2];
        float s_t  = cs_t[j]  + cs_t[j+1]  + cs_t[j+2];
        float s_pp = cs_pp[j] + cs_pp[j+1] + cs_pp[j+2];
        float s_tt = cs_tt[j] + cs_tt[j+1] + cs_tt[j+2];
        float s_pt = cs_pt[j] + cs_pt[j+1] + cs_pt[j+2];

        float up = s_p * inv9;
        float ut = s_t * inv9;
        float sig_p  = fmaf(s_pp, inv9, -up * up);
        float sig_t  = fmaf(s_tt, inv9, -ut * ut);
        float sig_co = fmaf(s_pt, inv9, -up * ut);

        float num = fmaf(2.f * up, ut, C1) * fmaf(2.f, sig_co, C2);
        float den = (fmaf(up, up, ut * ut) + C1) * (sig_p + sig_t + C2);
        float q = num * __builtin_amdgcn_rcpf(den);
        float v = fmaf(q, -0.5f, 0.5f);          // (1 - q) / 2
        resv[j] = fminf(fmaxf(v, 0.f), 1.f);
    }

    float4 res = make_float4(resv[0], resv[1], resv[2], resv[3]);
    *(float4*)(out + base + (size_t)(tile_y + oy) * IMG_W + tile_x + 4 * lx) = res;
}

extern "C" void kernel_launch(void* const* d_in, const int* in_sizes, int n_in,
                              void* d_out, int out_size, void* d_ws, size_t ws_size,
                              hipStream_t stream) {
    const float* pred   = (const float*)d_in[0];
    const float* target = (const float*)d_in[1];
    float* out = (float*)d_out;

    const int planes = in_sizes[0] / (IMG_H * IMG_W);   // 32*3 = 96

    dim3 block(16, 32);
    dim3 grid(IMG_W / TILE_W, IMG_H / TILE_H, planes);
    ssim_kernel<<<grid, block, 0, stream>>>(pred, target, out);
}

// Round 3
// 59.820 us; speedup vs baseline: 1.0583x; 1.0360x over previous
//
#include <hip/hip_runtime.h>

#define IMG_H 384
#define IMG_W 512
#define TILE_W 64
#define TILE_H 32
#define HALO_H (TILE_H + 2)     // 34
#define LDS_STRIDE 68           // words; halo col c (-1..64) lives at word c+2
#define NTHREADS 512

__device__ __forceinline__ int reflect_idx(int i, int n) {
    // ReflectionPad2d(1): -1 -> 1, n -> n-2
    if (i < 0) i = -i;
    else if (i >= n) i = 2 * n - 2 - i;
    return i;
}

__global__ __launch_bounds__(NTHREADS) void ssim_kernel(
    const float* __restrict__ pred,
    const float* __restrict__ target,
    float* __restrict__ out)
{
    __shared__ __align__(16) float lp[HALO_H * LDS_STRIDE];
    __shared__ __align__(16) float lt[HALO_H * LDS_STRIDE];

    const int plane  = blockIdx.z;
    const int tile_x = blockIdx.x * TILE_W;
    const int tile_y = blockIdx.y * TILE_H;
    const size_t base = (size_t)plane * (IMG_H * IMG_W);

    const int tid = threadIdx.y * 16 + threadIdx.x;    // 0..511

    // ---- interior staging: 2 arrays x 34 rows x 16 float4 = 1088 items ----
    // global float4 at col 4k -> words 4k+2..4k+5 -> two aligned ds_write_b64
    for (int i = tid; i < 2 * HALO_H * 16; i += NTHREADS) {
        int arr = (i >= HALO_H * 16);
        int j   = i - arr * (HALO_H * 16);
        int row = j >> 4;
        int k   = j & 15;
        int gy  = reflect_idx(tile_y - 1 + row, IMG_H);
        const float* __restrict__ src = arr ? target : pred;
        float4 v = *(const float4*)(src + base + (size_t)gy * IMG_W + tile_x + 4 * k);
        float* dst = (arr ? lt : lp) + row * LDS_STRIDE + 4 * k + 2;
        *(float2*)(dst)     = make_float2(v.x, v.y);
        *(float2*)(dst + 2) = make_float2(v.z, v.w);
    }

    // ---- edge staging: col -1 -> word 1, col 64 -> word 66 (34*2*2 = 136 scalars) ----
    if (tid < HALO_H * 4) {
        int row = tid >> 2;
        int sub = tid & 3;
        const float* __restrict__ src = (sub & 2) ? target : pred;
        float* dst = (sub & 2) ? lt : lp;
        int left = sub & 1;
        int gx = reflect_idx(tile_x + (left ? -1 : TILE_W), IMG_W);
        int gy = reflect_idx(tile_y - 1 + row, IMG_H);
        int word = left ? 1 : (TILE_W + 2);
        dst[row * LDS_STRIDE + word] = src[base + (size_t)gy * IMG_W + gx];
    }
    __syncthreads();

    // ---- compute: thread (oy, lx) -> outputs row oy, cols 4lx..4lx+3 ----
    const int oy = threadIdx.y;
    const int lx = threadIdx.x;

    float cs_p[6], cs_t[6], cs_pp[6], cs_tt[6], cs_pt[6];
    #pragma unroll
    for (int c = 0; c < 6; ++c) {
        cs_p[c] = 0.f; cs_t[c] = 0.f; cs_pp[c] = 0.f; cs_tt[c] = 0.f; cs_pt[c] = 0.f;
    }

    const float* rp = lp + oy * LDS_STRIDE + 4 * lx;
    const float* rt = lt + oy * LDS_STRIDE + 4 * lx;
    #pragma unroll
    for (int dy = 0; dy < 3; ++dy) {
        // words 4lx..4lx+7 = halo cols 4lx-2..4lx+5; need cols 4lx-1..4lx+4 = elems 1..6
        float4 pa = *(const float4*)(rp);
        float4 pb = *(const float4*)(rp + 4);
        float4 ta = *(const float4*)(rt);
        float4 tb = *(const float4*)(rt + 4);
        float pv[6] = {pa.y, pa.z, pa.w, pb.x, pb.y, pb.z};
        float tv[6] = {ta.y, ta.z, ta.w, tb.x, tb.y, tb.z};
        #pragma unroll
        for (int c = 0; c < 6; ++c) {
            float p = pv[c], t = tv[c];
            cs_p[c]  += p;
            cs_t[c]  += t;
            cs_pp[c] = fmaf(p, p, cs_pp[c]);
            cs_tt[c] = fmaf(t, t, cs_tt[c]);
            cs_pt[c] = fmaf(p, t, cs_pt[c]);
        }
        rp += LDS_STRIDE;
        rt += LDS_STRIDE;
    }

    const float C1 = 1e-4f;    // 0.01^2
    const float C2 = 9e-4f;    // 0.03^2
    const float inv9 = 1.0f / 9.0f;

    float resv[4];
    #pragma unroll
    for (int j = 0; j < 4; ++j) {
        float s_p  = cs_p[j]  + cs_p[j+1]  + cs_p[j+2];
        float s_t  = cs_t[j]  + cs_t[j+1]  + cs_t[j+2];
        float s_pp = cs_pp[j] + cs_pp[j+1] + cs_pp[j+2];
        float s_tt = cs_tt[j] + cs_tt[j+1] + cs_tt[j+2];
        float s_pt = cs_pt[j] + cs_pt[j+1] + cs_pt[j+2];

        float up = s_p * inv9;
        float ut = s_t * inv9;
        float sig_p  = fmaf(s_pp, inv9, -up * up);
        float sig_t  = fmaf(s_tt, inv9, -ut * ut);
        float sig_co = fmaf(s_pt, inv9, -up * ut);

        float num = fmaf(2.f * up, ut, C1) * fmaf(2.f, sig_co, C2);
        float den = (fmaf(up, up, ut * ut) + C1) * (sig_p + sig_t + C2);
        float q = num * __builtin_amdgcn_rcpf(den);
        float v = fmaf(q, -0.5f, 0.5f);          // (1 - q) / 2
        resv[j] = fminf(fmaxf(v, 0.f), 1.f);
    }

    float4 res = make_float4(resv[0], resv[1], resv[2], resv[3]);
    *(float4*)(out + base + (size_t)(tile_y + oy) * IMG_W + tile_x + 4 * lx) = res;
}

extern "C" void kernel_launch(void* const* d_in, const int* in_sizes, int n_in,
                              void* d_out, int out_size, void* d_ws, size_t ws_size,
                              hipStream_t stream) {
    const float* pred   = (const float*)d_in[0];
    const float* target = (const float*)d_in[1];
    float* out = (float*)d_out;

    const int planes = in_sizes[0] / (IMG_H * IMG_W);   // 32*3 = 96

    dim3 block(16, 32);
    dim3 grid(IMG_W / TILE_W, IMG_H / TILE_H, planes);
    ssim_kernel<<<grid, block, 0, stream>>>(pred, target, out);
}

// Round 4
// 43.287 us; speedup vs baseline: 1.4626x; 1.3819x over previous
//
#include <hip/hip_runtime.h>

typedef float v2f __attribute__((ext_vector_type(2)));

#define IMG_H 384
#define IMG_W 512
#define RPT 12          // output rows per thread
#define TY  4           // thread strips per block (y)
#define NLX 128         // threads across x (128 * 4 cols = 512 = full width)

struct RowH {
    v2f hx[4];     // (sum3_p, sum3_t) horizontal 3-tap for 4 outputs
    v2f hxx[4];    // (sum3_pp, sum3_tt)
    float hpt[4];  // sum3_pt
};

__device__ __forceinline__ void compute_row(
    const float* __restrict__ pred, const float* __restrict__ target,
    size_t base, int ry, int col0, int gxl, int gxr, RowH& h)
{
    int gy = ry;
    if (gy < 0) gy = -gy;
    else if (gy >= IMG_H) gy = 2 * IMG_H - 2 - gy;
    const float* rp = pred   + base + (size_t)gy * IMG_W;
    const float* rt = target + base + (size_t)gy * IMG_W;

    float4 p4 = *(const float4*)(rp + col0);
    float4 t4 = *(const float4*)(rt + col0);
    float pl = rp[gxl], pr = rp[gxr];
    float tl = rt[gxl], tr = rt[gxr];

    v2f x0 = {pl,   tl};
    v2f x1 = {p4.x, t4.x};
    v2f x2 = {p4.y, t4.y};
    v2f x3 = {p4.z, t4.z};
    v2f x4 = {p4.w, t4.w};
    v2f x5 = {pr,   tr};

    // horizontal 3-tap sums of (p,t), shared partials
    v2f a = x1 + x2, b = x3 + x4;
    h.hx[0] = x0 + a;  h.hx[1] = a + x3;
    h.hx[2] = x2 + b;  h.hx[3] = b + x5;

    // (pp,tt) packed squares
    v2f q0 = x0*x0, q1 = x1*x1, q2 = x2*x2, q3 = x3*x3, q4 = x4*x4, q5 = x5*x5;
    v2f aq = q1 + q2, bq = q3 + q4;
    h.hxx[0] = q0 + aq;  h.hxx[1] = aq + q3;
    h.hxx[2] = q2 + bq;  h.hxx[3] = bq + q5;

    // pt scalar chain
    float m0 = x0.x*x0.y, m1 = x1.x*x1.y, m2 = x2.x*x2.y,
          m3 = x3.x*x3.y, m4 = x4.x*x4.y, m5 = x5.x*x5.y;
    float am = m1 + m2, bm = m3 + m4;
    h.hpt[0] = m0 + am;  h.hpt[1] = am + m3;
    h.hpt[2] = m2 + bm;  h.hpt[3] = bm + m5;
}

__device__ __forceinline__ void emit_row(
    float* __restrict__ out, size_t base, int row, int col0,
    const RowH& A, const RowH& B, const RowH& C)
{
    const float C1 = 1e-4f;    // 0.01^2
    const float C2 = 9e-4f;    // 0.03^2
    const float inv9 = 1.0f / 9.0f;

    float rv[4];
    #pragma unroll
    for (int j = 0; j < 4; ++j) {
        v2f sx  = A.hx[j]  + B.hx[j]  + C.hx[j];    // (s_p, s_t)
        v2f sxx = A.hxx[j] + B.hxx[j] + C.hxx[j];   // (s_pp, s_tt)
        float spt = A.hpt[j] + B.hpt[j] + C.hpt[j];

        v2f u  = sx * inv9;                          // (up, ut)
        v2f uu = u * u;                              // (up^2, ut^2)
        v2f sig = sxx * inv9 - uu;                   // (sig_p, sig_t)
        float upt   = u.x * u.y;
        float sigco = fmaf(spt, inv9, -upt);

        float num = fmaf(2.f, upt, C1) * fmaf(2.f, sigco, C2);
        float den = (uu.x + uu.y + C1) * (sig.x + sig.y + C2);
        float q = num * __builtin_amdgcn_rcpf(den);
        rv[j] = fminf(fmaxf(fmaf(q, -0.5f, 0.5f), 0.f), 1.f);
    }
    float4 res = make_float4(rv[0], rv[1], rv[2], rv[3]);
    *(float4*)(out + base + (size_t)row * IMG_W + col0) = res;
}

__global__ __launch_bounds__(NLX * TY) void ssim_kernel(
    const float* __restrict__ pred,
    const float* __restrict__ target,
    float* __restrict__ out)
{
    const int lx   = threadIdx.x;            // 0..127
    const int col0 = 4 * lx;
    const size_t base = (size_t)blockIdx.z * (IMG_H * IMG_W);
    const int y0 = (blockIdx.y * TY + threadIdx.y) * RPT;

    const int gxl = col0 ? col0 - 1 : 1;                       // reflect x=-1 -> 1
    const int gxr = (col0 + 4 < IMG_W) ? col0 + 4 : IMG_W - 2; // reflect x=W -> W-2

    RowH A, B, Cc;
    compute_row(pred, target, base, y0 - 1, col0, gxl, gxr, A);
    compute_row(pred, target, base, y0,     col0, gxl, gxr, B);

    for (int r3 = 0; r3 < RPT; r3 += 3) {
        compute_row(pred, target, base, y0 + r3 + 1, col0, gxl, gxr, Cc);
        emit_row(out, base, y0 + r3,     col0, A, B, Cc);
        compute_row(pred, target, base, y0 + r3 + 2, col0, gxl, gxr, A);
        emit_row(out, base, y0 + r3 + 1, col0, B, Cc, A);
        compute_row(pred, target, base, y0 + r3 + 3, col0, gxl, gxr, B);
        emit_row(out, base, y0 + r3 + 2, col0, Cc, A, B);
    }
}

extern "C" void kernel_launch(void* const* d_in, const int* in_sizes, int n_in,
                              void* d_out, int out_size, void* d_ws, size_t ws_size,
                              hipStream_t stream) {
    const float* pred   = (const float*)d_in[0];
    const float* target = (const float*)d_in[1];
    float* out = (float*)d_out;

    const int planes = in_sizes[0] / (IMG_H * IMG_W);   // 32*3 = 96

    dim3 block(NLX, TY);                                 // 512 threads
    dim3 grid(1, IMG_H / (TY * RPT), planes);            // (1, 8, 96)
    ssim_kernel<<<grid, block, 0, stream>>>(pred, target, out);
}